// Round 15
// baseline (323.826 us; speedup 1.0000x reference)
//
#include <hip/hip_runtime.h>
#include <math.h>

// AutoLUT forward, MI355X. B=4, N=512, K=3 (PAD=2), Q=16, L=17, UPSCALE=4, SAMPLERS=3.
// R28: stage0 staging amortization — 256 blocks (1/CU), 4 px/thread.
//   Ledger: every stage0 variant (R17..R27) pays ~12 staging drains per CU
//   (4 block-generations x 3 samplers), each vmcnt(0)+barrier with no
//   co-resident work; all land 110-150us vs ~25us issue floor. Intra-block
//   scheduling moved <=5us. Fix: grid=256 so each CU runs ONE block; sampler
//   loop OUTER, 4-pixel loop INNER -> LUT staged 3x per CU total (12 -> 3
//   drains), staging traffic 256MB -> 64MB. Conv redone per sampler (same
//   FMA count, only 25 L1-warm loads repeat); per-sampler accumulation order
//   unchanged -> bit-identical. Keeps R26 async global_load_lds + R24
//   batch/pin gathers. stage1: byte-identical to R26 build (157+-3us).
static constexpr int B_ = 4;
static constexpr int N_ = 512;
static constexpr int N4_ = 2048;
static constexpr int NPIX = B_ * N_ * N_;      // 2^20
static constexpr int LUT_ROWS = 83521;         // 17^4
static constexpr int SPAD = 83584;             // LUT_ROWS padded to 16B multiple
static constexpr int ST0 = 4913, ST1 = 289, ST2 = 17, ST3 = 1;
static constexpr int SCHUNK = SPAD / 16;       // 5224 int4 chunks

__device__ __forceinline__ float fixw(float v) {
    v = rintf(v * 127.0f);
    return fminf(fmaxf(v, -127.0f), 127.0f);
}

// (3,83521) -> int8 with 16B-aligned per-sampler stride SPAD
__global__ void fix_lut0_kernel(const float* __restrict__ in, char* __restrict__ out) {
    int t = blockIdx.x * blockDim.x + threadIdx.x;
    int s = blockIdx.y;
    if (t < LUT_ROWS) out[(size_t)s * SPAD + t] = (char)(int)fixw(in[(size_t)s * LUT_ROWS + t]);
}

// (3,83521,16) -> uint8 biased by +127 (range 0..254)
__global__ void fix_lut1_kernel(const float4* __restrict__ in, uchar4* __restrict__ out, int n4) {
    int t = blockIdx.x * blockDim.x + threadIdx.x;
    if (t < n4) {
        float4 v = in[t];
        uchar4 o;
        o.x = (unsigned char)((int)fixw(v.x) + 127);
        o.y = (unsigned char)((int)fixw(v.y) + 127);
        o.z = (unsigned char)((int)fixw(v.z) + 127);
        o.w = (unsigned char)((int)fixw(v.w) + 127);
        out[t] = o;
    }
}

struct Simplex {
    int v[5];
    float w[5];   // pre-scaled by 1/16
};

// pack (f, stride) into a positive double: hi32 = f bits (f in [0,16) => sign 0,
// exponent never all-ones), lo32 = stride. double ordering == (f, stride) lex
// ordering for positive patterns, so fmax/fmin f64 sort both together in 1 op each.
__device__ __forceinline__ double pack_key(float f, unsigned stride) {
    unsigned long long u = ((unsigned long long)__float_as_uint(f) << 32) | stride;
    return __longlong_as_double((long long)u);
}
__device__ __forceinline__ float key_f(double k) {
    return __uint_as_float((unsigned)((unsigned long long)__double_as_longlong(k) >> 32));
}
__device__ __forceinline__ int key_s(double k) {
    return (int)(unsigned)__double_as_longlong(k);
}

// 4-D simplex lookup setup. floor/mod by 16 are exact in fp32 (pow-2); sort is a
// 5-CSW optimal network on f64-packed (f,stride) keys (ties -> zero-weight
// vertices, so tie ordering is irrelevant; f bits are kept exact).
__device__ __forceinline__ Simplex simplex4(float a, float b, float c, float d) {
    float fl0 = floorf(a * 0.0625f), fl1 = floorf(b * 0.0625f),
          fl2 = floorf(c * 0.0625f), fl3 = floorf(d * 0.0625f);
    float f0 = a - 16.0f * fl0, f1 = b - 16.0f * fl1,
          f2 = c - 16.0f * fl2, f3 = d - 16.0f * fl3;
    int l0 = min(max((int)fl0, 0), 15);
    int l1 = min(max((int)fl1, 0), 15);
    int l2 = min(max((int)fl2, 0), 15);
    int l3 = min(max((int)fl3, 0), 15);
    double k0 = pack_key(f0, (unsigned)ST0);
    double k1 = pack_key(f1, (unsigned)ST1);
    double k2 = pack_key(f2, (unsigned)ST2);
    double k3 = pack_key(f3, (unsigned)ST3);
#define CSWD(X, Y) { double mx_ = fmax(X, Y); Y = fmin(X, Y); X = mx_; }
    CSWD(k0, k1) CSWD(k2, k3) CSWD(k0, k2) CSWD(k1, k3) CSWD(k1, k2)
#undef CSWD
    Simplex s;
    s.v[0] = l0 * ST0 + l1 * ST1 + l2 * ST2 + l3;
    s.v[1] = s.v[0] + key_s(k0);
    s.v[2] = s.v[1] + key_s(k1);
    s.v[3] = s.v[2] + key_s(k2);
    s.v[4] = s.v[3] + key_s(k3);
    float g0 = key_f(k0), g1 = key_f(k1), g2 = key_f(k2), g3 = key_f(k3);
    s.w[0] = (16.0f - g0) * 0.0625f;
    s.w[1] = (g0 - g1) * 0.0625f;
    s.w[2] = (g1 - g2) * 0.0625f;
    s.w[3] = (g2 - g3) * 0.0625f;
    s.w[4] = g3 * 0.0625f;
    return s;
}

// Inverse tap map: which (di,dj) of rotation r reads clamped-neighborhood tap (a,c).
// (rotation r + edge-pad + VALID conv + rotate-back == clamped reads, orig frame)
__device__ __forceinline__ bool tap_for_r(int r, int a, int c, int& di, int& dj) {
    if (r == 0) { di = a - 2; dj = c - 2; return (a >= 2) && (c >= 2); }
    if (r == 1) { di = 2 - c; dj = a - 2; return (a >= 2) && (c <= 2); }
    if (r == 2) { di = 2 - a; dj = 2 - c; return (a <= 2) && (c <= 2); }
    di = c - 2; dj = 2 - a; return (a <= 2) && (c >= 2);
}

// unsigned-byte unpack-accumulate: selects v_cvt_f32_ubyte0..3 (1 op/elem)
__device__ __forceinline__ void acc4u(unsigned int q, float wv, float* oc) {
    oc[0] = fmaf(wv, (float)(q & 0xffu), oc[0]);
    oc[1] = fmaf(wv, (float)((q >> 8) & 0xffu), oc[1]);
    oc[2] = fmaf(wv, (float)((q >> 16) & 0xffu), oc[2]);
    oc[3] = fmaf(wv, (float)(q >> 24), oc[3]);
}

__global__ __launch_bounds__(1024, 4) void stage0_kernel(
    const float* __restrict__ x,       // (4,512,512), [0,1]
    const char* __restrict__ lut0q,    // (3,SPAD) int8 fixed, padded stride
    const float* __restrict__ samp0,   // (3,4,3,3)
    const float* __restrict__ sbias0,  // (3,4)
    float* __restrict__ x1)            // out: (4,512,512), integer-valued 0..255
{
    __shared__ char luts[SPAD];        // one sampler's LUT at a time; 1 blk/CU

    // 64x64 region per block (4 sub-tiles of 32x32); 4 px/thread.
    // grid = 256 = one block per CU -> LUT staged 3x per CU TOTAL.
    int b   = blockIdx.x >> 6;
    int reg = blockIdx.x & 63;
    int i0 = (reg >> 3) << 6;
    int j0 = (reg & 7) << 6;
    int ti = threadIdx.x >> 5;         // 0..31
    int tj = threadIdx.x & 31;         // 0..31
    const int tid = threadIdx.x;
    const float* xb = x + (size_t)b * N_ * N_;

    float pred[4] = { 0.0f, 0.0f, 0.0f, 0.0f };

    for (int s = 0; s < 3; ++s) {
        // ---- stage LUT s into LDS (async direct L2->LDS DMA; zero VGPRs)
        __syncthreads();               // previous-iteration readers done
        {
            const char* src = lut0q + (size_t)s * SPAD;
            #pragma unroll
            for (int k = 0; k < 5; ++k) {
                int off = (tid + k * 1024) * 16;
                __builtin_amdgcn_global_load_lds(
                    (const __attribute__((address_space(1))) void*)(src + off),
                    (__attribute__((address_space(3))) void*)(luts + off),
                    16, 0, 0);
            }
            if (tid < SCHUNK - 5120) {
                int off = (tid + 5120) * 16;
                __builtin_amdgcn_global_load_lds(
                    (const __attribute__((address_space(1))) void*)(src + off),
                    (__attribute__((address_space(3))) void*)(luts + off),
                    16, 0, 0);
            }
        }
        __syncthreads();               // implicit s_waitcnt vmcnt(0) first

        const float* sb = sbias0 + s * 4;
        const float* w  = samp0 + s * 36;

        // ---- 4 pixels consume the staged LUT (amortization)
        #pragma unroll
        for (int t = 0; t < 4; ++t) {
            int i = i0 + ((t >> 1) << 5) + ti;
            int j = j0 + ((t & 1) << 5) + tj;

            // per-sampler conv (same FMA count/order as merged; loads L1-warm)
            float vals[4][4];
            #pragma unroll
            for (int r = 0; r < 4; ++r)
                #pragma unroll
                for (int ch = 0; ch < 4; ++ch) vals[r][ch] = 0.0f;
            #pragma unroll
            for (int a = 0; a < 5; ++a) {
                int ri = min(max(i - 2 + a, 0), N_ - 1);
                const float* row = xb + ri * N_;
                #pragma unroll
                for (int c = 0; c < 5; ++c) {
                    int ci = min(max(j - 2 + c, 0), N_ - 1);
                    float px = row[ci] * 255.0f;
                    #pragma unroll
                    for (int r = 0; r < 4; ++r) {
                        int di, dj;
                        if (tap_for_r(r, a, c, di, dj)) {
                            #pragma unroll
                            for (int ch = 0; ch < 4; ++ch)
                                vals[r][ch] += w[ch * 9 + di * 3 + dj] * px;
                        }
                    }
                }
            }

            // 4 simplexes, then ALL 20 LDS byte-gathers batched (R24 form)
            Simplex sx[4];
            #pragma unroll
            for (int r = 0; r < 4; ++r)
                sx[r] = simplex4(vals[r][0] + sb[0], vals[r][1] + sb[1],
                                 vals[r][2] + sb[2], vals[r][3] + sb[3]);

            float p[4][5];
            #pragma unroll
            for (int r = 0; r < 4; ++r)
                #pragma unroll
                for (int v = 0; v < 5; ++v)
                    p[r][v] = (float)luts[sx[r].v[v]];

            float acc = 0.0f;
            #pragma unroll
            for (int r = 0; r < 4; ++r) {
                // pin: interp(r) runs while later rotations' ds_reads drain
                asm volatile("" : "+v"(p[r][0]), "+v"(p[r][1]), "+v"(p[r][2]),
                                  "+v"(p[r][3]), "+v"(p[r][4]));
                float o = sx[r].w[0] * p[r][0] + sx[r].w[1] * p[r][1]
                        + sx[r].w[2] * p[r][2] + sx[r].w[3] * p[r][3]
                        + sx[r].w[4] * p[r][4];
                acc = rintf(acc + o);   // ste_round after each rotation
            }
            pred[t] += acc;             // same sampler-order accumulation
        }
    }

    #pragma unroll
    for (int t = 0; t < 4; ++t) {
        int i = i0 + ((t >> 1) << 5) + ti;
        int j = j0 + ((t & 1) << 5) + tj;
        x1[(size_t)b * N_ * N_ + i * N_ + j] =
            rintf(fminf(fmaxf(pred[t] / 12.0f + 127.0f, 0.0f), 255.0f));
    }
}

__global__ __launch_bounds__(256, 1) void stage1_kernel(
    const float* __restrict__ x,        // original (4,512,512), [0,1]
    const float* __restrict__ x1,       // stage-0 out, 0..255
    const unsigned char* __restrict__ lut1q, // (3,83521,16) uint8 = fixw+127
    const float* __restrict__ samp1,    // (3,4,3,3)
    const float* __restrict__ sbias1,   // (3,4)
    const float* __restrict__ resw1,    // (3,2,2)
    float* __restrict__ out)            // (4,2048,2048)
{
    // 16x16 pixel tile per block; wave = 16x4 patch (R13 mapping)
    int b    = blockIdx.x >> 10;
    int tile = blockIdx.x & 1023;
    int i = ((tile >> 5) << 4) + (threadIdx.x >> 4);
    int j = ((tile & 31) << 4) + (threadIdx.x & 15);
    const float* xb  = x  + (size_t)b * N_ * N_;
    const float* x1b = x1 + (size_t)b * N_ * N_;

    float tot[16];
    #pragma unroll
    for (int k = 0; k < 16; ++k) tot[k] = 0.0f;

    // per-sampler phases; conv loads (L1-resident) of sampler s+1 overlap
    // the unpack burst of sampler s.
    for (int s = 0; s < 3; ++s) {
        const float* w  = samp1 + s * 36;
        const unsigned char* lut = lut1q + (size_t)s * LUT_ROWS * 16;
        float rws[4];
        #pragma unroll
        for (int ch = 0; ch < 4; ++ch)
            rws[ch] = fminf(fmaxf(resw1[s * 4 + ch], 0.0f), 1.0f);

        // ---- conv phase, blend folded per tap:
        //   vals[r][ch] = sb + sum_t w_t * (pc + rw*dq),  dq = pp - pc
        //   (exact-math equal to rw*(vp+sb) + (1-rw)*(vc+sb); conv is linear)
        float vals[4][4];
        #pragma unroll
        for (int r = 0; r < 4; ++r)
            #pragma unroll
            for (int ch = 0; ch < 4; ++ch) vals[r][ch] = sbias1[s * 4 + ch];

        #pragma unroll
        for (int a = 0; a < 5; ++a) {
            int ri = min(max(i - 2 + a, 0), N_ - 1);
            const float* r1 = x1b + ri * N_;
            const float* r0 = xb + ri * N_;
            #pragma unroll
            for (int c = 0; c < 5; ++c) {
                int ci = min(max(j - 2 + c, 0), N_ - 1);
                float pc = r1[ci];
                float dq = r0[ci] * 255.0f - pc;
                float q[4];
                #pragma unroll
                for (int ch = 0; ch < 4; ++ch)
                    q[ch] = fmaf(rws[ch], dq, pc);   // blended pixel, per channel
                #pragma unroll
                for (int r = 0; r < 4; ++r) {
                    int di, dj;
                    if (tap_for_r(r, a, c, di, dj)) {
                        #pragma unroll
                        for (int ch = 0; ch < 4; ++ch)
                            vals[r][ch] += w[ch * 9 + di * 3 + dj] * q[ch];
                    }
                }
            }
        }

        // ---- all 4 simplexes up front (pure VALU, no loads)
        Simplex sx[4];
        #pragma unroll
        for (int r = 0; r < 4; ++r)
            sx[r] = simplex4(vals[r][0], vals[r][1], vals[r][2], vals[r][3]);

        // ---- issue ALL 20 gathers batched: one latency exposure per sampler
        uint4 g[4][5];
        #pragma unroll
        for (int r = 0; r < 4; ++r)
            #pragma unroll
            for (int v = 0; v < 5; ++v)
                g[r][v] = *(const uint4*)(lut + (size_t)sx[r].v[v] * 16);

        // ---- unpack/scatter burst (same arithmetic order as before)
        float acc[16];
        #pragma unroll
        for (int k = 0; k < 16; ++k) acc[k] = 0.0f;

        #pragma unroll
        for (int r = 0; r < 4; ++r) {
            // pin this rotation's gather values: loads may not sink below here,
            // so unpack(r) runs while rotations r+1..3 loads are still in flight
            #pragma unroll
            for (int v = 0; v < 5; ++v)
                asm volatile("" : "+v"(g[r][v].x), "+v"(g[r][v].y),
                                  "+v"(g[r][v].z), "+v"(g[r][v].w));
            float oc[16];
            #pragma unroll
            for (int k = 0; k < 16; ++k) oc[k] = 0.0f;
            #pragma unroll
            for (int v = 0; v < 5; ++v) {
                float wv = sx[r].w[v];
                acc4u(g[r][v].x, wv, oc);
                acc4u(g[r][v].y, wv, oc + 4);
                acc4u(g[r][v].z, wv, oc + 8);
                acc4u(g[r][v].w, wv, oc + 12);
            }
            // remove the +127 bias: sum(ws) == 1 (computed S keeps fp error tiny)
            float S = sx[r].w[0] + sx[r].w[1] + sx[r].w[2] + sx[r].w[3] + sx[r].w[4];
            float bias = 127.0f * S;
            #pragma unroll
            for (int k = 0; k < 16; ++k) oc[k] -= bias;
            // scatter rotated 4x4 sub-block into original-orientation accumulator
            #pragma unroll
            for (int u = 0; u < 4; ++u)
                #pragma unroll
                for (int v2 = 0; v2 < 4; ++v2) {
                    int k = 4 * u + v2;
                    int c = (r == 0) ? (4 * u + v2)
                          : (r == 1) ? (4 * (3 - v2) + u)
                          : (r == 2) ? (4 * (3 - u) + (3 - v2))
                                     : (4 * v2 + (3 - u));
                    acc[k] = rintf(acc[k] + oc[c]);   // ste_round per rotation
                }
        }
        #pragma unroll
        for (int k = 0; k < 16; ++k) tot[k] += acc[k];
    }

    float* ob = out + (size_t)b * N4_ * N4_ + (size_t)(i * 4) * N4_ + (j * 4);
    #pragma unroll
    for (int u = 0; u < 4; ++u) {
        float4 val;
        val.x = rintf(fminf(fmaxf(tot[4 * u + 0] / 3.0f, 0.0f), 255.0f)) * (1.0f / 255.0f);
        val.y = rintf(fminf(fmaxf(tot[4 * u + 1] / 3.0f, 0.0f), 255.0f)) * (1.0f / 255.0f);
        val.z = rintf(fminf(fmaxf(tot[4 * u + 2] / 3.0f, 0.0f), 255.0f)) * (1.0f / 255.0f);
        val.w = rintf(fminf(fmaxf(tot[4 * u + 3] / 3.0f, 0.0f), 255.0f)) * (1.0f / 255.0f);
        *(float4*)(ob + (size_t)u * N4_) = val;
    }
}

extern "C" void kernel_launch(void* const* d_in, const int* in_sizes, int n_in,
                              void* d_out, int out_size, void* d_ws, size_t ws_size,
                              hipStream_t stream) {
    const float* x      = (const float*)d_in[0];
    const float* lut0   = (const float*)d_in[1];
    const float* lut1   = (const float*)d_in[2];
    const float* samp0  = (const float*)d_in[3];
    const float* samp1  = (const float*)d_in[4];
    const float* sbias0 = (const float*)d_in[5];
    const float* sbias1 = (const float*)d_in[6];
    const float* resw1  = (const float*)d_in[7];
    float* out = (float*)d_out;
    char* ws   = (char*)d_ws;

    const int N_L1 = 3 * LUT_ROWS * 16;       // 4,009,008
    size_t off_x1 = 0;                        // 4 MB of floats
    size_t off_l0 = (size_t)NPIX * sizeof(float);
    size_t off_l1 = (off_l0 + (size_t)3 * SPAD + 15) & ~(size_t)15;

    float* x1 = (float*)(ws + off_x1);
    char* l0q = ws + off_l0;                  // (3, SPAD) padded
    unsigned char* l1q = (unsigned char*)(ws + off_l1);

    const int threads = 256;

    dim3 g0((LUT_ROWS + threads - 1) / threads, 3);
    fix_lut0_kernel<<<g0, threads, 0, stream>>>(lut0, l0q);
    fix_lut1_kernel<<<(N_L1 / 4 + threads - 1) / threads, threads, 0, stream>>>(
        (const float4*)lut1, (uchar4*)l1q, N_L1 / 4);
    stage0_kernel<<<256, 1024, 0, stream>>>(x, l0q, samp0, sbias0, x1);
    stage1_kernel<<<NPIX / threads, threads, 0, stream>>>(x, x1, l1q, samp1, sbias1, resw1, out);
}

// Round 16
// 273.791 us; speedup vs baseline: 1.1827x; 1.1827x over previous
//
#include <hip/hip_runtime.h>
#include <math.h>

// AutoLUT forward, MI355X. B=4, N=512, K=3 (PAD=2), Q=16, L=17, UPSCALE=4, SAMPLERS=3.
// R29 == R26 restored byte-for-byte (measured session-best 274.0us).
//   Stage0 ledger closed after 9 structural variants (R17..R28): best = R26's
//   {1024-thr, 32x32 tile, merged conv, async global_load_lds staging,
//   batch-after-barrier gathers, pinned interp} at ~116us; all alternatives
//   (no-LDS, 512-thr, reg-staging T14, 2-blk/CU 79.5KB, persistent 1-blk/CU)
//   measured worse by 30-60us. stage1 stable at 157-172us @ 82% VALUBusy
//   (issue-bound). R28 (current state) regressed -> restore the best build.
static constexpr int B_ = 4;
static constexpr int N_ = 512;
static constexpr int N4_ = 2048;
static constexpr int NPIX = B_ * N_ * N_;      // 2^20
static constexpr int LUT_ROWS = 83521;         // 17^4
static constexpr int SPAD = 83584;             // LUT_ROWS padded to 16B multiple
static constexpr int ST0 = 4913, ST1 = 289, ST2 = 17, ST3 = 1;
static constexpr int SCHUNK = SPAD / 16;       // 5224 int4 chunks

__device__ __forceinline__ float fixw(float v) {
    v = rintf(v * 127.0f);
    return fminf(fmaxf(v, -127.0f), 127.0f);
}

// (3,83521) -> int8 with 16B-aligned per-sampler stride SPAD
__global__ void fix_lut0_kernel(const float* __restrict__ in, char* __restrict__ out) {
    int t = blockIdx.x * blockDim.x + threadIdx.x;
    int s = blockIdx.y;
    if (t < LUT_ROWS) out[(size_t)s * SPAD + t] = (char)(int)fixw(in[(size_t)s * LUT_ROWS + t]);
}

// (3,83521,16) -> uint8 biased by +127 (range 0..254)
__global__ void fix_lut1_kernel(const float4* __restrict__ in, uchar4* __restrict__ out, int n4) {
    int t = blockIdx.x * blockDim.x + threadIdx.x;
    if (t < n4) {
        float4 v = in[t];
        uchar4 o;
        o.x = (unsigned char)((int)fixw(v.x) + 127);
        o.y = (unsigned char)((int)fixw(v.y) + 127);
        o.z = (unsigned char)((int)fixw(v.z) + 127);
        o.w = (unsigned char)((int)fixw(v.w) + 127);
        out[t] = o;
    }
}

struct Simplex {
    int v[5];
    float w[5];   // pre-scaled by 1/16
};

// pack (f, stride) into a positive double: hi32 = f bits (f in [0,16) => sign 0,
// exponent never all-ones), lo32 = stride. double ordering == (f, stride) lex
// ordering for positive patterns, so fmax/fmin f64 sort both together in 1 op each.
__device__ __forceinline__ double pack_key(float f, unsigned stride) {
    unsigned long long u = ((unsigned long long)__float_as_uint(f) << 32) | stride;
    return __longlong_as_double((long long)u);
}
__device__ __forceinline__ float key_f(double k) {
    return __uint_as_float((unsigned)((unsigned long long)__double_as_longlong(k) >> 32));
}
__device__ __forceinline__ int key_s(double k) {
    return (int)(unsigned)__double_as_longlong(k);
}

// 4-D simplex lookup setup. floor/mod by 16 are exact in fp32 (pow-2); sort is a
// 5-CSW optimal network on f64-packed (f,stride) keys (ties -> zero-weight
// vertices, so tie ordering is irrelevant; f bits are kept exact).
__device__ __forceinline__ Simplex simplex4(float a, float b, float c, float d) {
    float fl0 = floorf(a * 0.0625f), fl1 = floorf(b * 0.0625f),
          fl2 = floorf(c * 0.0625f), fl3 = floorf(d * 0.0625f);
    float f0 = a - 16.0f * fl0, f1 = b - 16.0f * fl1,
          f2 = c - 16.0f * fl2, f3 = d - 16.0f * fl3;
    int l0 = min(max((int)fl0, 0), 15);
    int l1 = min(max((int)fl1, 0), 15);
    int l2 = min(max((int)fl2, 0), 15);
    int l3 = min(max((int)fl3, 0), 15);
    double k0 = pack_key(f0, (unsigned)ST0);
    double k1 = pack_key(f1, (unsigned)ST1);
    double k2 = pack_key(f2, (unsigned)ST2);
    double k3 = pack_key(f3, (unsigned)ST3);
#define CSWD(X, Y) { double mx_ = fmax(X, Y); Y = fmin(X, Y); X = mx_; }
    CSWD(k0, k1) CSWD(k2, k3) CSWD(k0, k2) CSWD(k1, k3) CSWD(k1, k2)
#undef CSWD
    Simplex s;
    s.v[0] = l0 * ST0 + l1 * ST1 + l2 * ST2 + l3;
    s.v[1] = s.v[0] + key_s(k0);
    s.v[2] = s.v[1] + key_s(k1);
    s.v[3] = s.v[2] + key_s(k2);
    s.v[4] = s.v[3] + key_s(k3);
    float g0 = key_f(k0), g1 = key_f(k1), g2 = key_f(k2), g3 = key_f(k3);
    s.w[0] = (16.0f - g0) * 0.0625f;
    s.w[1] = (g0 - g1) * 0.0625f;
    s.w[2] = (g1 - g2) * 0.0625f;
    s.w[3] = (g2 - g3) * 0.0625f;
    s.w[4] = g3 * 0.0625f;
    return s;
}

// Inverse tap map: which (di,dj) of rotation r reads clamped-neighborhood tap (a,c).
// (rotation r + edge-pad + VALID conv + rotate-back == clamped reads, orig frame)
__device__ __forceinline__ bool tap_for_r(int r, int a, int c, int& di, int& dj) {
    if (r == 0) { di = a - 2; dj = c - 2; return (a >= 2) && (c >= 2); }
    if (r == 1) { di = 2 - c; dj = a - 2; return (a >= 2) && (c <= 2); }
    if (r == 2) { di = 2 - a; dj = 2 - c; return (a <= 2) && (c <= 2); }
    di = c - 2; dj = 2 - a; return (a <= 2) && (c >= 2);
}

// unsigned-byte unpack-accumulate: selects v_cvt_f32_ubyte0..3 (1 op/elem)
__device__ __forceinline__ void acc4u(unsigned int q, float wv, float* oc) {
    oc[0] = fmaf(wv, (float)(q & 0xffu), oc[0]);
    oc[1] = fmaf(wv, (float)((q >> 8) & 0xffu), oc[1]);
    oc[2] = fmaf(wv, (float)((q >> 16) & 0xffu), oc[2]);
    oc[3] = fmaf(wv, (float)(q >> 24), oc[3]);
}

__global__ __launch_bounds__(1024, 4) void stage0_kernel(
    const float* __restrict__ x,       // (4,512,512), [0,1]
    const char* __restrict__ lut0q,    // (3,SPAD) int8 fixed, padded stride
    const float* __restrict__ samp0,   // (3,4,3,3)
    const float* __restrict__ sbias0,  // (3,4)
    float* __restrict__ x1)            // out: (4,512,512), integer-valued 0..255
{
    __shared__ char luts[SPAD];        // one sampler's LUT at a time; 1 blk/CU

    // 32x32 pixel tile per block; wave = 32x2 patch (R21 mapping)
    int b    = blockIdx.x >> 8;
    int tile = blockIdx.x & 255;
    int i = ((tile >> 4) << 5) + (threadIdx.x >> 5);
    int j = ((tile & 15) << 5) + (threadIdx.x & 31);
    const int tid = threadIdx.x;
    const float* xb = x + (size_t)b * N_ * N_;

    // ---- single conv pass: each neighborhood pixel loaded ONCE, feeds all
    //      3 samplers x 4 rotations x 4 channels (same tap order as before).
    float vals[3][4][4];
    #pragma unroll
    for (int s = 0; s < 3; ++s)
        #pragma unroll
        for (int r = 0; r < 4; ++r)
            #pragma unroll
            for (int ch = 0; ch < 4; ++ch) vals[s][r][ch] = 0.0f;
    #pragma unroll
    for (int a = 0; a < 5; ++a) {
        int ri = min(max(i - 2 + a, 0), N_ - 1);
        const float* row = xb + ri * N_;
        #pragma unroll
        for (int c = 0; c < 5; ++c) {
            int ci = min(max(j - 2 + c, 0), N_ - 1);
            float px = row[ci] * 255.0f;
            #pragma unroll
            for (int r = 0; r < 4; ++r) {
                int di, dj;
                if (tap_for_r(r, a, c, di, dj)) {
                    #pragma unroll
                    for (int s = 0; s < 3; ++s)
                        #pragma unroll
                        for (int ch = 0; ch < 4; ++ch)
                            vals[s][r][ch] += samp0[s * 36 + ch * 9 + di * 3 + dj] * px;
                }
            }
        }
    }

    float pred = 0.0f;
    #pragma unroll   // keeps vals[s] statically indexed (no scratch)
    for (int s = 0; s < 3; ++s) {
        // ---- stage LUT s into LDS via async direct L2->LDS DMA:
        //      ZERO staging VGPRs (no int4 temps), loads don't round-trip
        //      through the register file. LDS dest = wave-uniform base +
        //      lane*16 (linear layout, legal pattern). __syncthreads emits
        //      the vmcnt(0) that drains them.
        __syncthreads();               // previous-iteration readers done
        {
            const char* src = lut0q + (size_t)s * SPAD;
            #pragma unroll
            for (int k = 0; k < 5; ++k) {
                int off = (tid + k * 1024) * 16;
                __builtin_amdgcn_global_load_lds(
                    (const __attribute__((address_space(1))) void*)(src + off),
                    (__attribute__((address_space(3))) void*)(luts + off),
                    16, 0, 0);
            }
            if (tid < SCHUNK - 5120) {
                int off = (tid + 5120) * 16;
                __builtin_amdgcn_global_load_lds(
                    (const __attribute__((address_space(1))) void*)(src + off),
                    (__attribute__((address_space(3))) void*)(luts + off),
                    16, 0, 0);
            }
        }
        __syncthreads();               // implicit s_waitcnt vmcnt(0) first

        // ---- AFTER the barrier: 4 simplexes, then ALL 20 LDS byte-gathers
        //      batched (R24 form) -> 3 latency exposures per pixel.
        const float* sb = sbias0 + s * 4;
        Simplex sx[4];
        #pragma unroll
        for (int r = 0; r < 4; ++r)
            sx[r] = simplex4(vals[s][r][0] + sb[0], vals[s][r][1] + sb[1],
                             vals[s][r][2] + sb[2], vals[s][r][3] + sb[3]);

        float p[4][5];
        #pragma unroll
        for (int r = 0; r < 4; ++r)
            #pragma unroll
            for (int v = 0; v < 5; ++v)
                p[r][v] = (float)luts[sx[r].v[v]];

        float acc = 0.0f;
        #pragma unroll
        for (int r = 0; r < 4; ++r) {
            // pin: this rotation's values may not be re-sunk below; interp(r)
            // runs while later rotations' ds_reads are still outstanding
            asm volatile("" : "+v"(p[r][0]), "+v"(p[r][1]), "+v"(p[r][2]),
                              "+v"(p[r][3]), "+v"(p[r][4]));
            float o = sx[r].w[0] * p[r][0] + sx[r].w[1] * p[r][1]
                    + sx[r].w[2] * p[r][2] + sx[r].w[3] * p[r][3]
                    + sx[r].w[4] * p[r][4];
            acc = rintf(acc + o);   // ste_round after each rotation
        }
        pred += acc;
    }
    x1[(size_t)b * N_ * N_ + i * N_ + j] =
        rintf(fminf(fmaxf(pred / 12.0f + 127.0f, 0.0f), 255.0f));
}

__global__ __launch_bounds__(256, 1) void stage1_kernel(
    const float* __restrict__ x,        // original (4,512,512), [0,1]
    const float* __restrict__ x1,       // stage-0 out, 0..255
    const unsigned char* __restrict__ lut1q, // (3,83521,16) uint8 = fixw+127
    const float* __restrict__ samp1,    // (3,4,3,3)
    const float* __restrict__ sbias1,   // (3,4)
    const float* __restrict__ resw1,    // (3,2,2)
    float* __restrict__ out)            // (4,2048,2048)
{
    // 16x16 pixel tile per block; wave = 16x4 patch (R13 mapping)
    int b    = blockIdx.x >> 10;
    int tile = blockIdx.x & 1023;
    int i = ((tile >> 5) << 4) + (threadIdx.x >> 4);
    int j = ((tile & 31) << 4) + (threadIdx.x & 15);
    const float* xb  = x  + (size_t)b * N_ * N_;
    const float* x1b = x1 + (size_t)b * N_ * N_;

    float tot[16];
    #pragma unroll
    for (int k = 0; k < 16; ++k) tot[k] = 0.0f;

    // per-sampler phases; conv loads (L1-resident) of sampler s+1 overlap
    // the unpack burst of sampler s.
    for (int s = 0; s < 3; ++s) {
        const float* w  = samp1 + s * 36;
        const unsigned char* lut = lut1q + (size_t)s * LUT_ROWS * 16;
        float rws[4];
        #pragma unroll
        for (int ch = 0; ch < 4; ++ch)
            rws[ch] = fminf(fmaxf(resw1[s * 4 + ch], 0.0f), 1.0f);

        // ---- conv phase, blend folded per tap:
        //   vals[r][ch] = sb + sum_t w_t * (pc + rw*dq),  dq = pp - pc
        //   (exact-math equal to rw*(vp+sb) + (1-rw)*(vc+sb); conv is linear)
        float vals[4][4];
        #pragma unroll
        for (int r = 0; r < 4; ++r)
            #pragma unroll
            for (int ch = 0; ch < 4; ++ch) vals[r][ch] = sbias1[s * 4 + ch];

        #pragma unroll
        for (int a = 0; a < 5; ++a) {
            int ri = min(max(i - 2 + a, 0), N_ - 1);
            const float* r1 = x1b + ri * N_;
            const float* r0 = xb + ri * N_;
            #pragma unroll
            for (int c = 0; c < 5; ++c) {
                int ci = min(max(j - 2 + c, 0), N_ - 1);
                float pc = r1[ci];
                float dq = r0[ci] * 255.0f - pc;
                float q[4];
                #pragma unroll
                for (int ch = 0; ch < 4; ++ch)
                    q[ch] = fmaf(rws[ch], dq, pc);   // blended pixel, per channel
                #pragma unroll
                for (int r = 0; r < 4; ++r) {
                    int di, dj;
                    if (tap_for_r(r, a, c, di, dj)) {
                        #pragma unroll
                        for (int ch = 0; ch < 4; ++ch)
                            vals[r][ch] += w[ch * 9 + di * 3 + dj] * q[ch];
                    }
                }
            }
        }

        // ---- all 4 simplexes up front (pure VALU, no loads)
        Simplex sx[4];
        #pragma unroll
        for (int r = 0; r < 4; ++r)
            sx[r] = simplex4(vals[r][0], vals[r][1], vals[r][2], vals[r][3]);

        // ---- issue ALL 20 gathers batched: one latency exposure per sampler
        uint4 g[4][5];
        #pragma unroll
        for (int r = 0; r < 4; ++r)
            #pragma unroll
            for (int v = 0; v < 5; ++v)
                g[r][v] = *(const uint4*)(lut + (size_t)sx[r].v[v] * 16);

        // ---- unpack/scatter burst (same arithmetic order as before)
        float acc[16];
        #pragma unroll
        for (int k = 0; k < 16; ++k) acc[k] = 0.0f;

        #pragma unroll
        for (int r = 0; r < 4; ++r) {
            // pin this rotation's gather values: loads may not sink below here,
            // so unpack(r) runs while rotations r+1..3 loads are still in flight
            #pragma unroll
            for (int v = 0; v < 5; ++v)
                asm volatile("" : "+v"(g[r][v].x), "+v"(g[r][v].y),
                                  "+v"(g[r][v].z), "+v"(g[r][v].w));
            float oc[16];
            #pragma unroll
            for (int k = 0; k < 16; ++k) oc[k] = 0.0f;
            #pragma unroll
            for (int v = 0; v < 5; ++v) {
                float wv = sx[r].w[v];
                acc4u(g[r][v].x, wv, oc);
                acc4u(g[r][v].y, wv, oc + 4);
                acc4u(g[r][v].z, wv, oc + 8);
                acc4u(g[r][v].w, wv, oc + 12);
            }
            // remove the +127 bias: sum(ws) == 1 (computed S keeps fp error tiny)
            float S = sx[r].w[0] + sx[r].w[1] + sx[r].w[2] + sx[r].w[3] + sx[r].w[4];
            float bias = 127.0f * S;
            #pragma unroll
            for (int k = 0; k < 16; ++k) oc[k] -= bias;
            // scatter rotated 4x4 sub-block into original-orientation accumulator
            #pragma unroll
            for (int u = 0; u < 4; ++u)
                #pragma unroll
                for (int v2 = 0; v2 < 4; ++v2) {
                    int k = 4 * u + v2;
                    int c = (r == 0) ? (4 * u + v2)
                          : (r == 1) ? (4 * (3 - v2) + u)
                          : (r == 2) ? (4 * (3 - u) + (3 - v2))
                                     : (4 * v2 + (3 - u));
                    acc[k] = rintf(acc[k] + oc[c]);   // ste_round per rotation
                }
        }
        #pragma unroll
        for (int k = 0; k < 16; ++k) tot[k] += acc[k];
    }

    float* ob = out + (size_t)b * N4_ * N4_ + (size_t)(i * 4) * N4_ + (j * 4);
    #pragma unroll
    for (int u = 0; u < 4; ++u) {
        float4 val;
        val.x = rintf(fminf(fmaxf(tot[4 * u + 0] / 3.0f, 0.0f), 255.0f)) * (1.0f / 255.0f);
        val.y = rintf(fminf(fmaxf(tot[4 * u + 1] / 3.0f, 0.0f), 255.0f)) * (1.0f / 255.0f);
        val.z = rintf(fminf(fmaxf(tot[4 * u + 2] / 3.0f, 0.0f), 255.0f)) * (1.0f / 255.0f);
        val.w = rintf(fminf(fmaxf(tot[4 * u + 3] / 3.0f, 0.0f), 255.0f)) * (1.0f / 255.0f);
        *(float4*)(ob + (size_t)u * N4_) = val;
    }
}

extern "C" void kernel_launch(void* const* d_in, const int* in_sizes, int n_in,
                              void* d_out, int out_size, void* d_ws, size_t ws_size,
                              hipStream_t stream) {
    const float* x      = (const float*)d_in[0];
    const float* lut0   = (const float*)d_in[1];
    const float* lut1   = (const float*)d_in[2];
    const float* samp0  = (const float*)d_in[3];
    const float* samp1  = (const float*)d_in[4];
    const float* sbias0 = (const float*)d_in[5];
    const float* sbias1 = (const float*)d_in[6];
    const float* resw1  = (const float*)d_in[7];
    float* out = (float*)d_out;
    char* ws   = (char*)d_ws;

    const int N_L1 = 3 * LUT_ROWS * 16;       // 4,009,008
    size_t off_x1 = 0;                        // 4 MB of floats
    size_t off_l0 = (size_t)NPIX * sizeof(float);
    size_t off_l1 = (off_l0 + (size_t)3 * SPAD + 15) & ~(size_t)15;

    float* x1 = (float*)(ws + off_x1);
    char* l0q = ws + off_l0;                  // (3, SPAD) padded
    unsigned char* l1q = (unsigned char*)(ws + off_l1);

    const int threads = 256;

    dim3 g0((LUT_ROWS + threads - 1) / threads, 3);
    fix_lut0_kernel<<<g0, threads, 0, stream>>>(lut0, l0q);
    fix_lut1_kernel<<<(N_L1 / 4 + threads - 1) / threads, threads, 0, stream>>>(
        (const float4*)lut1, (uchar4*)l1q, N_L1 / 4);
    stage0_kernel<<<NPIX / 1024, 1024, 0, stream>>>(x, l0q, samp0, sbias0, x1);
    stage1_kernel<<<NPIX / threads, threads, 0, stream>>>(x, x1, l1q, samp1, sbias1, resw1, out);
}